// Round 8
// baseline (231.393 us; speedup 1.0000x reference)
//
#include <hip/hip_runtime.h>
#include <hip/hip_bf16.h>

// Problem constants: B,L,M,D,K,STRIDE = 32,32768,32,128,16,8
#define Bn 32
#define Ln 32768
#define Mn 32
#define Dn 128
#define Pn 4095            // (L - K)/STRIDE + 1
#define KKn 512            // M*K  (GEMM reduction dim)

typedef short  bf16x8 __attribute__((ext_vector_type(8)));  // 8 bf16 = 4 VGPRs
typedef short  bf16x4 __attribute__((ext_vector_type(4)));  // 8 B
typedef float  f32x4  __attribute__((ext_vector_type(4)));

static __device__ __forceinline__ unsigned short f2bf(float f) {
  __hip_bfloat16 h = __float2bfloat16(f);
  return *reinterpret_cast<unsigned short*>(&h);
}

static __device__ __forceinline__ bf16x4 cvt4(const float4& a) {
  union { bf16x4 v; unsigned short u[4]; } bu;
  bu.u[0] = f2bf(a.x); bu.u[1] = f2bf(a.y); bu.u[2] = f2bf(a.z); bu.u[3] = f2bf(a.w);
  return bu.v;
}

// Granule-level (16 B) xor swizzle on bf16 granules; mask = patch-row bits.
// A-fragment = ONE granule, so no multi-granule pairing constraint.
static __device__ __forceinline__ int phi(int g) {
  return g ^ ((g >> 5) & 7);
}

// ---------------------------------------------------------------------------
// Prep: conv_w (D,M,K) fp32 -> fragment-ready bf16 table in d_ws (128 KiB).
// kk = k*32 + m; B-frag lane d, kk = t*32 + quad*8 + j
//   -> wswz[((kk>>3)*128 + d)*8 + (kk&7)]  (one 16-B load per fragment)
// ---------------------------------------------------------------------------
__global__ __launch_bounds__(256) void prep_w_kernel(const float* __restrict__ w,
                                                     unsigned short* __restrict__ wswz) {
  int idx = blockIdx.x * 256 + threadIdx.x;   // 0..65535
  int j = idx & 7;
  int d = (idx >> 3) & 127;
  int g = idx >> 10;
  int kk = g * 8 + j;
  int k = kk >> 5;
  int m = kk & 31;
  wswz[idx] = f2bf(w[(d << 9) + (m << 4) + k]);   // w[d][m][k]
}

// ---------------------------------------------------------------------------
// Main: 32 patches x 128 d per block, 4 waves split by d.  bf16 LDS slab
// (16.9 KB) -> 8 blocks/CU = 32 waves/CU (full occupancy).  TLP, not ILP,
// hides latency (rounds 2-6: 16 waves/CU pins at ~81-84 us regardless of
// staging structure).  A-frag = one ds_read_b128 (no cvt in K-loop).
// Round-7 crash fix: staging stride was j*512 (skipped half the slab, read
// 28 KB past x, wrote past LDS) -> correct stride j*256.
// ---------------------------------------------------------------------------
__global__ __launch_bounds__(256, 8) void gemm_pe_kernel(
    const float* __restrict__ x,          // (B, L, M) fp32
    const float* __restrict__ ts,         // (B, L)    fp32, sorted along L
    const unsigned short* __restrict__ wswz,
    const float* __restrict__ bias,       // (D,)
    float* __restrict__ out) {            // (B, P, D) fp32

  __shared__ unsigned short xs[1056 * 8]; // 1056 bf16 granules = 16,896 B (264 rows)
  __shared__ float tsl[32];

  const int b    = blockIdx.y;
  const int tile = blockIdx.x;            // 32-patch tile, 0..127
  const int tid  = threadIdx.x;
  const int lane = tid & 63;
  const int wv   = tid >> 6;              // d-block 0..3
  const int mrow = lane & 15;
  const int quad = lane >> 4;

  // slab = 2112 fp32 granules (16 B each) at fp32-granule offset slab0g.
  // fp32 granule G <-> bf16 granule o = G>>1, half h = G&1.
  const size_t slab0g = (((size_t)b * Ln * Mn) >> 2) + (size_t)tile * 2048;
  const float* xg0 = x + (slab0g << 2);

  // ---- staging batch 1: fp32 granules G = j*256 + tid, j=0..3 ----
  float4 fA[4];
  #pragma unroll
  for (int j = 0; j < 4; ++j)
    fA[j] = *reinterpret_cast<const float4*>(xg0 + (((size_t)j * 256 + tid) << 2));
  __builtin_amdgcn_sched_barrier(0);
  #pragma unroll
  for (int j = 0; j < 4; ++j) {
    int G = j * 256 + tid;                // 0..1023
    int o = G >> 1, h = G & 1;
    *reinterpret_cast<bf16x4*>(&xs[phi(o) * 8 + h * 4]) = cvt4(fA[j]);
  }

  // ---- staging batch 2: G = j*256 + tid, j=4..7, + 64-granule tail + ts ----
  float4 fB[4];
  #pragma unroll
  for (int j = 0; j < 4; ++j)
    fB[j] = *reinterpret_cast<const float4*>(xg0 + (((size_t)(j + 4) * 256 + tid) << 2));
  float4 ft = make_float4(0.f, 0.f, 0.f, 0.f);
  if (tid < 64) {
    // tail rows 256..263: past x end only for b=31,tile=127 -> clamp.
    size_t gg = slab0g + 2048 + tid;
    const size_t xg_max = (((size_t)Bn * Ln * Mn) >> 2) - 1;
    if (gg > xg_max) gg = xg_max;         // finite garbage; feeds only patch 4095
    ft = *reinterpret_cast<const float4*>(x + (gg << 2));
  }
  float tsv = 0.f;
  if (tid < 32)
    tsv = ts[(size_t)b * Ln + tile * 256 + tid * 8 + 7];  // sorted -> median
  __builtin_amdgcn_sched_barrier(0);
  #pragma unroll
  for (int j = 0; j < 4; ++j) {
    int G = (j + 4) * 256 + tid;          // 1024..2047
    int o = G >> 1, h = G & 1;
    *reinterpret_cast<bf16x4*>(&xs[phi(o) * 8 + h * 4]) = cvt4(fB[j]);
  }
  if (tid < 64) {
    int G = 2048 + tid;                   // bf16 granules 1024..1055
    int o = G >> 1, h = G & 1;
    *reinterpret_cast<bf16x4*>(&xs[phi(o) * 8 + h * 4]) = cvt4(ft);
  }
  if (tid < 32) tsl[tid] = tsv;

  // ---- B-frag ring preload (global, L2/L3-hot) before the barrier ----
  const unsigned short* bq = wswz + (((quad << 7) + (wv << 5) + mrow) << 3);
  bf16x8 bp[2][2];
  #pragma unroll
  for (int j = 0; j < 2; ++j) {
    bp[j][0] = *reinterpret_cast<const bf16x8*>(bq + j * 4096);
    bp[j][1] = *reinterpret_cast<const bf16x8*>(bq + j * 4096 + 128);
  }

  __syncthreads();

  // ---- K-loop: 16 steps of K=32.  A-frag (pt,t): bf16 granule
  //      g = (pt*16+mrow)*32 + t*4 + quad, one ds_read_b128 at phi(g). ----
  int agbase[2];
  #pragma unroll
  for (int pt = 0; pt < 2; ++pt) agbase[pt] = (pt * 16 + mrow) * 32 + quad;

  f32x4 acc[2][2] = {};

  #pragma unroll
  for (int t = 0; t < 16; ++t) {
    const int cur = t & 1;
    bf16x8 af[2];
    #pragma unroll
    for (int pt = 0; pt < 2; ++pt)
      af[pt] = *reinterpret_cast<const bf16x8*>(&xs[phi(agbase[pt] + t * 4) * 8]);
    bf16x8 bc0 = bp[cur][0], bc1 = bp[cur][1];
    if (t < 14) {
      bp[cur][0] = *reinterpret_cast<const bf16x8*>(bq + (t + 2) * 4096);
      bp[cur][1] = *reinterpret_cast<const bf16x8*>(bq + (t + 2) * 4096 + 128);
    }
    #pragma unroll
    for (int pt = 0; pt < 2; ++pt) {
      acc[pt][0] = __builtin_amdgcn_mfma_f32_16x16x32_bf16(af[pt], bc0, acc[pt][0], 0, 0, 0);
      acc[pt][1] = __builtin_amdgcn_mfma_f32_16x16x32_bf16(af[pt], bc1, acc[pt][1], 0, 0, 0);
    }
  }

  // ---- epilogue: + bias + PE.  C/D: col(mrow)=d, row(quad*4+reg)=patch ----
  const int d0 = wv * 32 + mrow;
  const float NEG_C = -0.14391156831212810f;            // -ln(10000)/64
  const float div0  = __expf(NEG_C * (float)(d0 >> 1));
  const float div1  = __expf(NEG_C * (float)((d0 + 16) >> 1));
  const float phs   = (d0 & 1) ? 1.5707963267948966f : 0.0f;
  const float bias0 = bias[d0];
  const float bias1 = bias[d0 + 16];

  #pragma unroll
  for (int pt = 0; pt < 2; ++pt) {
    const int plbase = pt * 16 + quad * 4;
    f32x4 med4 = *reinterpret_cast<const f32x4*>(&tsl[plbase]);
    const int pbase = tile * 32 + plbase;
    float* ob = out + ((size_t)b * Pn + pbase) * Dn + d0;
    #pragma unroll
    for (int reg = 0; reg < 4; ++reg) {
      if (pbase + reg < Pn) {
        float m = med4[reg];
        float pe0 = __sinf(m * div0 + phs);
        float pe1 = __sinf(m * div1 + phs);
        ob[reg * Dn]      = acc[pt][0][reg] + bias0 + pe0;
        ob[reg * Dn + 16] = acc[pt][1][reg] + bias1 + pe1;
      }
    }
  }
}

extern "C" void kernel_launch(void* const* d_in, const int* in_sizes, int n_in,
                              void* d_out, int out_size, void* d_ws, size_t ws_size,
                              hipStream_t stream) {
  const float* x      = (const float*)d_in[0];   // (32, 32768, 32)
  const float* ts     = (const float*)d_in[1];   // (32, 32768)
  const float* conv_w = (const float*)d_in[2];   // (128, 32, 16)
  const float* conv_b = (const float*)d_in[3];   // (128,)
  float* out = (float*)d_out;
  unsigned short* wswz = (unsigned short*)d_ws;  // 512*128 bf16 = 128 KiB

  prep_w_kernel<<<256, 256, 0, stream>>>(conv_w, wswz);
  gemm_pe_kernel<<<dim3(128, Bn), 256, 0, stream>>>(x, ts, wswz, conv_b, out);
}